// Round 1
// 455.695 us; speedup vs baseline: 1.2909x; 1.2909x over previous
//
#include <hip/hip_runtime.h>

#define D 64
#define EPT 16    // edges per thread in partition
#define BK 256    // rows per dst bucket
#define KMAX 1024 // max bucket count supported by scan

// ---- bf16 helpers ----
static __device__ __forceinline__ unsigned short f2bf(float f) {
    unsigned int u = __float_as_uint(f);
    unsigned int r = (u + 0x7FFFu + ((u >> 16) & 1u)) >> 16;
    return (unsigned short)r;
}
static __device__ __forceinline__ float bflo(unsigned int u) {
    return __uint_as_float(u << 16);
}
static __device__ __forceinline__ float bfhi(unsigned int u) {
    return __uint_as_float(u & 0xFFFF0000u);
}

// ---------------- init: fp32 acc (flagged rows only) + bf16 cur ----------------
__global__ void init_kernel(const float4* __restrict__ user_w,
                            const float4* __restrict__ item_w,
                            float4* __restrict__ acc,
                            ushort4* __restrict__ curb,
                            const int* __restrict__ flags,
                            int n_user4, int n_tot4) {
    int i = blockIdx.x * blockDim.x + threadIdx.x;
    if (i >= n_tot4) return;
    float4 v = (i < n_user4) ? user_w[i] : item_w[i - n_user4];
    ushort4 b;
    b.x = f2bf(v.x); b.y = f2bf(v.y); b.z = f2bf(v.z); b.w = f2bf(v.w);
    curb[i] = b;
    if (flags[i >> 4]) acc[i] = v;   // acc only read at flagged rows
}

// ---------------- flag + compact list of batch-needed rows ----------------
__global__ void flag_kernel(const int* __restrict__ bu,
                            const int* __restrict__ bp,
                            const int* __restrict__ bn,
                            int* __restrict__ flags,
                            int* __restrict__ list,
                            int* __restrict__ n_list,
                            int U_, int B_) {
    int t = blockIdx.x * blockDim.x + threadIdx.x;
    int node = -1;
    if (t < 3 * B_) {
        if (t < B_)            node = bu[t];
        else if (t < 2 * B_)   node = U_ + bp[t - B_];
        else                   node = U_ + bn[t - 2 * B_];
    }
    int old = 1;
    if (node >= 0) old = atomicExch(&flags[node], 1);
    unsigned long long m = __ballot(old == 0);
    int lane = threadIdx.x & 63;
    int myoff = __popcll(m & ((1ull << lane) - 1ull));
    int total = __popcll(m);
    int bse = 0;
    if (lane == 0 && total) bse = atomicAdd(n_list, total);
    bse = __shfl(bse, 0, 64);
    if (old == 0) list[bse + myoff] = node;
}

// ---------------- partition: LDS histogram + fixed-stride bucket reserve ----
// st entry: {src, (val_bf16<<16) | dst_off8}. Bucket k occupies st[k*S .. ).
__global__ void partition_kernel(const int* __restrict__ src,
                                 const int* __restrict__ dst,
                                 const float* __restrict__ val,
                                 int* __restrict__ g_pos,
                                 int2* __restrict__ st,
                                 int S_, int K_, int E_) {
    __shared__ int cnt[KMAX];
    __shared__ int base[KMAX];
    for (int k = threadIdx.x; k < K_; k += 256) cnt[k] = 0;
    __syncthreads();
    int b0 = blockIdx.x * (256 * EPT);
    int myk[EPT], myr[EPT], mysrc[EPT];
    unsigned mypk[EPT];
#pragma unroll
    for (int e = 0; e < EPT; ++e) {
        int i = b0 + e * 256 + threadIdx.x;
        if (i < E_) {
            int d = dst[i];
            int k = d >> 8;
            myk[e] = k;
            mysrc[e] = src[i];
            mypk[e] = ((unsigned)f2bf(val[i]) << 16) | (unsigned)(d & (BK - 1));
            myr[e] = atomicAdd(&cnt[k], 1);
        } else {
            myk[e] = -1;
        }
    }
    __syncthreads();
    for (int k = threadIdx.x; k < K_; k += 256) {
        int c = cnt[k];
        base[k] = c ? (k * S_ + atomicAdd(&g_pos[k], c)) : 0;
    }
    __syncthreads();
#pragma unroll
    for (int e = 0; e < EPT; ++e) {
        if (myk[e] >= 0)
            st[base[myk[e]] + myr[e]] = make_int2(mysrc[e], (int)mypk[e]);
    }
}

// single block (1024 threads): exclusive scan of K (<=1024) bucket counts.
__global__ void scan_bkt_kernel(const int* __restrict__ cnt,
                                int* __restrict__ base, int K_) {
    __shared__ int sh[KMAX];
    int tid = threadIdx.x;
    int v = (tid < K_) ? cnt[tid] : 0;
    sh[tid] = v;
    __syncthreads();
    for (int off = 1; off < KMAX; off <<= 1) {
        int t = (tid >= off) ? sh[tid - off] : 0;
        __syncthreads();
        sh[tid] += t;
        __syncthreads();
    }
    if (tid < K_) base[tid] = sh[tid] - v;
}

// place: one block per bucket; local degrees + row_span in LDS, then scatter
// from strided st into the compact L2-resident col_val window.
__global__ void place_kernel(const int2* __restrict__ st,
                             const int* __restrict__ g_cnt,
                             const int* __restrict__ bkt_base,
                             int2* __restrict__ row_span,
                             int2* __restrict__ col_val,
                             int S_, int N_) {
    __shared__ int ldeg[BK];
    __shared__ int sh[BK];
    __shared__ int lcur[BK];
    int b = blockIdx.x;
    int tid = threadIdx.x;
    int rbeg = b << 8;
    int sbeg = b * S_;
    int cnt = g_cnt[b];
    int cbeg = bkt_base[b];
    ldeg[tid] = 0;
    __syncthreads();
    for (int i = tid; i < cnt; i += 256)
        atomicAdd(&ldeg[(unsigned)st[sbeg + i].y & (BK - 1u)], 1);
    __syncthreads();
    int v = ldeg[tid];
    sh[tid] = v;
    __syncthreads();
    for (int off = 1; off < BK; off <<= 1) {
        int t = (tid >= off) ? sh[tid - off] : 0;
        __syncthreads();
        sh[tid] += t;
        __syncthreads();
    }
    int excl = sh[tid] - v;
    lcur[tid] = excl;
    int gi = rbeg + tid;
    if (gi < N_) row_span[gi] = make_int2(cbeg + excl, cbeg + excl + v);
    __syncthreads();
    for (int i = tid; i < cnt; i += 256) {
        int2 cv = st[sbeg + i];
        int pcur = cbeg + atomicAdd(&lcur[(unsigned)cv.y & (BK - 1u)], 1);
        col_val[pcur] = cv;
    }
}

// ---------------- shared row-accumulate body ----------------
static __device__ __forceinline__ void spmm_row_body(
        int beg, int end, int lane, int q, int lid,
        const int2* __restrict__ col_val, const uint4* __restrict__ xb,
        float& s0, float& s1, float& s2, float& s3,
        float& s4, float& s5, float& s6, float& s7) {
    for (int base = beg; base < end; base += 64) {
        int e = base + lane;
        int c = 0;
        float v = 0.f;
        if (e < end) {
            int2 cv = col_val[e];
            c = cv.x;
            v = bfhi((unsigned)cv.y);   // val in high 16 bits
        }
        int m8 = (min(64, end - base) + 7) & ~7;
        int j = 0;
        // 2x unroll: two independent gathers in flight per step
        for (; j + 16 <= m8; j += 16) {
            int cj0 = __shfl(c, j + q, 64);
            float vj0 = __shfl(v, j + q, 64);
            int cj1 = __shfl(c, j + 8 + q, 64);
            float vj1 = __shfl(v, j + 8 + q, 64);
            uint4 t0 = xb[cj0 * 8 + lid];
            uint4 t1 = xb[cj1 * 8 + lid];
            s0 += vj0 * bflo(t0.x); s1 += vj0 * bfhi(t0.x);
            s2 += vj0 * bflo(t0.y); s3 += vj0 * bfhi(t0.y);
            s4 += vj0 * bflo(t0.z); s5 += vj0 * bfhi(t0.z);
            s6 += vj0 * bflo(t0.w); s7 += vj0 * bfhi(t0.w);
            s0 += vj1 * bflo(t1.x); s1 += vj1 * bfhi(t1.x);
            s2 += vj1 * bflo(t1.y); s3 += vj1 * bfhi(t1.y);
            s4 += vj1 * bflo(t1.z); s5 += vj1 * bfhi(t1.z);
            s6 += vj1 * bflo(t1.w); s7 += vj1 * bfhi(t1.w);
        }
        if (j < m8) {
            int cj = __shfl(c, j + q, 64);
            float vj = __shfl(v, j + q, 64);
            uint4 t = xb[cj * 8 + lid];
            s0 += vj * bflo(t.x); s1 += vj * bfhi(t.x);
            s2 += vj * bflo(t.y); s3 += vj * bfhi(t.y);
            s4 += vj * bflo(t.z); s5 += vj * bfhi(t.z);
            s6 += vj * bflo(t.w); s7 += vj * bfhi(t.w);
        }
    }
#pragma unroll
    for (int off = 32; off >= 8; off >>= 1) {
        s0 += __shfl_xor(s0, off, 64);
        s1 += __shfl_xor(s1, off, 64);
        s2 += __shfl_xor(s2, off, 64);
        s3 += __shfl_xor(s3, off, 64);
        s4 += __shfl_xor(s4, off, 64);
        s5 += __shfl_xor(s5, off, 64);
        s6 += __shfl_xor(s6, off, 64);
        s7 += __shfl_xor(s7, off, 64);
    }
}

// ---------------- CSR gather SpMM (full layers 1-2) ----------------
__global__ void spmm_csr_kernel(const int2* __restrict__ row_span,
                                const int2* __restrict__ col_val,
                                const uint4* __restrict__ xb,
                                uint4* __restrict__ nxtb,
                                float4* __restrict__ acc,
                                const int* __restrict__ flags,
                                int N_) {
    int row = (int)((blockIdx.x * blockDim.x + threadIdx.x) >> 6);
    int lane = threadIdx.x & 63;
    if (row >= N_) return;
    int q = lane >> 3;
    int lid = lane & 7;
    int2 sp = row_span[row];
    float s0 = 0, s1 = 0, s2 = 0, s3 = 0, s4 = 0, s5 = 0, s6 = 0, s7 = 0;
    spmm_row_body(sp.x, sp.y, lane, q, lid, col_val, xb,
                  s0, s1, s2, s3, s4, s5, s6, s7);
    if (q == 0) {
        uint4 b;
        b.x = (unsigned)f2bf(s0) | ((unsigned)f2bf(s1) << 16);
        b.y = (unsigned)f2bf(s2) | ((unsigned)f2bf(s3) << 16);
        b.z = (unsigned)f2bf(s4) | ((unsigned)f2bf(s5) << 16);
        b.w = (unsigned)f2bf(s6) | ((unsigned)f2bf(s7) << 16);
        nxtb[row * 8 + lid] = b;
        if (flags[row]) {
            float4* ap = acc + row * 16 + lid * 2;
            float4 a0 = ap[0];
            a0.x += s0; a0.y += s1; a0.z += s2; a0.w += s3;
            ap[0] = a0;
            float4 a1 = ap[1];
            a1.x += s4; a1.y += s5; a1.z += s6; a1.w += s7;
            ap[1] = a1;
        }
    }
}

// ---------------- layer-3 SpMM over compacted flagged rows only ----------------
__global__ void spmm_rows_kernel(const int2* __restrict__ row_span,
                                 const int2* __restrict__ col_val,
                                 const uint4* __restrict__ xb,
                                 float4* __restrict__ acc,
                                 const int* __restrict__ list,
                                 const int* __restrict__ n_list) {
    int w = (int)((blockIdx.x * blockDim.x + threadIdx.x) >> 6);
    if (w >= *n_list) return;
    int row = list[w];
    int lane = threadIdx.x & 63;
    int q = lane >> 3;
    int lid = lane & 7;
    int2 sp = row_span[row];
    float s0 = 0, s1 = 0, s2 = 0, s3 = 0, s4 = 0, s5 = 0, s6 = 0, s7 = 0;
    spmm_row_body(sp.x, sp.y, lane, q, lid, col_val, xb,
                  s0, s1, s2, s3, s4, s5, s6, s7);
    if (q == 0) {
        float4* ap = acc + row * 16 + lid * 2;
        float4 a0 = ap[0];
        a0.x += s0; a0.y += s1; a0.z += s2; a0.w += s3;
        ap[0] = a0;
        float4 a1 = ap[1];
        a1.x += s4; a1.y += s5; a1.z += s6; a1.w += s7;
        ap[1] = a1;
    }
}

// ---------------- epilogue ----------------
__global__ void final_kernel(const float* __restrict__ acc,
                             const float* __restrict__ user_w,
                             const float* __restrict__ item_w,
                             const int* __restrict__ bu,
                             const int* __restrict__ bp,
                             const int* __restrict__ bn,
                             float* __restrict__ out,
                             float* __restrict__ red,
                             int U_, int B_) {
    __shared__ float pr[4];
    int w = (int)((blockIdx.x * blockDim.x + threadIdx.x) >> 6);
    int lane = threadIdx.x & 63;
    bool valid = (w < B_);
    float ps = 0.f, ns = 0.f, r = 0.f;
    if (valid) {
        int iu = bu[w], ip = bp[w], in_ = bn[w];
        const float scale = 0.25f;  // 1/(L+1)
        float u = acc[(long)iu * D + lane] * scale;
        float p = acc[(long)(U_ + ip) * D + lane] * scale;
        float g = acc[(long)(U_ + in_) * D + lane] * scale;
        ps = u * p;
        ns = u * g;
        float u0 = user_w[(long)iu * D + lane];
        float p0 = item_w[(long)ip * D + lane];
        float n0 = item_w[(long)in_ * D + lane];
        r = u0 * u0 + p0 * p0 + n0 * n0;
    }
#pragma unroll
    for (int off = 32; off; off >>= 1) {
        ps += __shfl_down(ps, off, 64);
        ns += __shfl_down(ns, off, 64);
        r  += __shfl_down(r, off, 64);
    }
    if (lane == 0) pr[threadIdx.x >> 6] = r;
    __syncthreads();
    if (threadIdx.x == 0)
        red[blockIdx.x] = pr[0] + pr[1] + pr[2] + pr[3];
    if (valid && lane == 0) {
        out[w] = ps;
        out[B_ + w] = ns;
    }
}

// single block: sum nblk partials -> out[2B]
__global__ void reduce_kernel(const float* __restrict__ red,
                              float* __restrict__ out_scalar, int nblk) {
    __shared__ float sh[256];
    float s = 0.f;
    for (int i = threadIdx.x; i < nblk; i += 256) s += red[i];
    sh[threadIdx.x] = s;
    __syncthreads();
    for (int off = 128; off; off >>= 1) {
        if (threadIdx.x < off) sh[threadIdx.x] += sh[threadIdx.x + off];
        __syncthreads();
    }
    if (threadIdx.x == 0) *out_scalar = sh[0];
}

// ---------------- launch ----------------
extern "C" void kernel_launch(void* const* d_in, const int* in_sizes, int n_in,
                              void* d_out, int out_size, void* d_ws, size_t ws_size,
                              hipStream_t stream) {
    const int*   edge_src = (const int*)d_in[0];
    const int*   edge_dst = (const int*)d_in[1];
    const float* edge_val = (const float*)d_in[2];
    const float* user_w   = (const float*)d_in[3];
    const float* item_w   = (const float*)d_in[4];
    const int*   bu       = (const int*)d_in[5];
    const int*   bp       = (const int*)d_in[6];
    const int*   bn       = (const int*)d_in[7];

    int E_ = in_sizes[0];
    int U_ = in_sizes[3] / D;
    int I_ = in_sizes[4] / D;
    int B_ = in_sizes[5];
    int N_ = U_ + I_;
    long ND = (long)N_ * D;
    int K_ = (N_ + BK - 1) >> 8;                       // 256-row dst buckets
    int S_ = ((E_ / K_) * 3 / 2 + 255) & ~255;         // 1.5x mean bucket slack

    // ---- workspace layout ----
    char* p = (char*)d_ws;
    int2* col_val  = (int2*)p;   p += (size_t)E_ * sizeof(int2);
    int2* row_span = (int2*)p;   p += (size_t)N_ * sizeof(int2);
    int*  bkt_base = (int*)p;    p += KMAX * sizeof(int);
    float* red     = (float*)p;  p += 4096 * sizeof(float);
    char* zb = p;                                   // zeroed block start
    int*  g_pos    = (int*)p;    p += KMAX * sizeof(int);
    int*  n_list   = (int*)p;    p += 256;          // padded
    int*  flags    = (int*)p;    p += (size_t)N_ * sizeof(int);
    size_t zbytes  = (size_t)(p - zb);
    int*  list     = (int*)p;    p += (size_t)3 * B_ * sizeof(int);
    p = (char*)(((uintptr_t)p + 255) & ~(uintptr_t)255);
    // overlay: staged edges (build phase) then embeddings (compute phase)
    int2* st = (int2*)p;
    float* acc = (float*)p;
    unsigned short* curb = (unsigned short*)(acc + ND);
    unsigned short* nxtb = curb + ND;
    float* out = (float*)d_out;

    int n4 = (int)(ND / 4);
    int nu4 = U_ * D / 4;

    // ---- CSR build (no count kernel: fixed-stride bucket reservation) ----
    hipMemsetAsync(zb, 0, zbytes, stream);
    partition_kernel<<<(E_ + 256 * EPT - 1) / (256 * EPT), 256, 0, stream>>>(
        edge_src, edge_dst, edge_val, g_pos, st, S_, K_, E_);
    scan_bkt_kernel<<<1, KMAX, 0, stream>>>(g_pos, bkt_base, K_);
    place_kernel<<<K_, 256, 0, stream>>>(st, g_pos, bkt_base, row_span,
                                         col_val, S_, N_);

    // ---- batch-row flags + compacted list ----
    flag_kernel<<<(3 * B_ + 255) / 256, 256, 0, stream>>>(
        bu, bp, bn, flags, list, n_list, U_, B_);

    // ---- embeddings init (overwrites staged region; stream-ordered) ----
    init_kernel<<<(n4 + 255) / 256, 256, 0, stream>>>(
        (const float4*)user_w, (const float4*)item_w,
        (float4*)acc, (ushort4*)curb, flags, nu4, n4);

    // ---- propagation: layers 1-2 full, layer 3 only batch rows ----
    spmm_csr_kernel<<<(N_ + 3) / 4, 256, 0, stream>>>(
        row_span, col_val, (const uint4*)curb, (uint4*)nxtb, (float4*)acc,
        flags, N_);
    spmm_csr_kernel<<<(N_ + 3) / 4, 256, 0, stream>>>(
        row_span, col_val, (const uint4*)nxtb, (uint4*)curb, (float4*)acc,
        flags, N_);
    spmm_rows_kernel<<<(3 * B_ + 3) / 4, 256, 0, stream>>>(
        row_span, col_val, (const uint4*)curb, (float4*)acc, list, n_list);

    // ---- epilogue ----
    int nblk = (B_ * 64 + 255) / 256;
    final_kernel<<<nblk, 256, 0, stream>>>(
        acc, user_w, item_w, bu, bp, bn, out, red, U_, B_);
    reduce_kernel<<<1, 256, 0, stream>>>(red, out + 2 * B_, nblk);
}

// Round 3
// 408.857 us; speedup vs baseline: 1.4388x; 1.1146x over previous
//
#include <hip/hip_runtime.h>

#define D 64
#define BK 256     // rows per dst bucket
#define KMAX 1024  // max bucket count supported
#define PCH 6144   // edges per partition block (LDS staging = 48 KB)
#define PEPT 6     // edges per thread (1024 threads)

// ---- bf16 helpers ----
static __device__ __forceinline__ unsigned short f2bf(float f) {
    unsigned int u = __float_as_uint(f);
    unsigned int r = (u + 0x7FFFu + ((u >> 16) & 1u)) >> 16;
    return (unsigned short)r;
}
static __device__ __forceinline__ float bflo(unsigned int u) {
    return __uint_as_float(u << 16);
}
static __device__ __forceinline__ float bfhi(unsigned int u) {
    return __uint_as_float(u & 0xFFFF0000u);
}

// ---------------- init: fp32 acc (flagged rows only) + bf16 cur ----------------
__global__ void init_kernel(const float4* __restrict__ user_w,
                            const float4* __restrict__ item_w,
                            float4* __restrict__ acc,
                            ushort4* __restrict__ curb,
                            const int* __restrict__ flags,
                            int n_user4, int n_tot4) {
    int i = blockIdx.x * blockDim.x + threadIdx.x;
    if (i >= n_tot4) return;
    float4 v = (i < n_user4) ? user_w[i] : item_w[i - n_user4];
    ushort4 b;
    b.x = f2bf(v.x); b.y = f2bf(v.y); b.z = f2bf(v.z); b.w = f2bf(v.w);
    curb[i] = b;
    if (flags[i >> 4]) acc[i] = v;   // acc only read at flagged rows
}

// ---------------- flag + compact list of batch-needed rows ----------------
__global__ void flag_kernel(const int* __restrict__ bu,
                            const int* __restrict__ bp,
                            const int* __restrict__ bn,
                            int* __restrict__ flags,
                            int* __restrict__ list,
                            int* __restrict__ n_list,
                            int U_, int B_) {
    int t = blockIdx.x * blockDim.x + threadIdx.x;
    int node = -1;
    if (t < 3 * B_) {
        if (t < B_)            node = bu[t];
        else if (t < 2 * B_)   node = U_ + bp[t - B_];
        else                   node = U_ + bn[t - 2 * B_];
    }
    int old = 1;
    if (node >= 0) old = atomicExch(&flags[node], 1);
    unsigned long long m = __ballot(old == 0);
    int lane = threadIdx.x & 63;
    int myoff = __popcll(m & ((1ull << lane) - 1ull));
    int total = __popcll(m);
    int bse = 0;
    if (lane == 0 && total) bse = atomicAdd(n_list, total);
    bse = __shfl(bse, 0, 64);
    if (old == 0) list[bse + myoff] = node;
}

// ---------------- partition: LDS-staged bucket sort, coalesced writeout ----
// st entry: {src, (val_bf16<<16) | dst_off8}. Bucket k occupies st[k*S .. ).
// Staged entry packs bucket id into src high bits (needs N < 2^20, K <= 1024).
// LDS: 48 KB staging + 12 KB aux = 60 KB -> 2 blocks/CU (120/160 KB).
__global__ void __launch_bounds__(1024)
partition_kernel(const int* __restrict__ src,
                 const int* __restrict__ dst,
                 const float* __restrict__ val,
                 int* __restrict__ g_pos,
                 int2* __restrict__ st,
                 int S_, int K_, int E_) {
    __shared__ int2 stg[PCH];     // block-local bucket-sorted staging
    __shared__ int cnt[KMAX];
    __shared__ int sh[KMAX];      // inclusive scan of cnt
    __shared__ int gb[KMAX];      // global base minus local base
    int tid = threadIdx.x;
    for (int k = tid; k < K_; k += 1024) cnt[k] = 0;
    __syncthreads();
    int b0 = blockIdx.x * PCH;
    int nc = min(PCH, E_ - b0);
    int myk[PEPT], myr[PEPT], mysrc[PEPT];
    unsigned mypk[PEPT];
#pragma unroll
    for (int e = 0; e < PEPT; ++e) {
        int i = b0 + e * 1024 + tid;
        if (i < E_) {
            int d = dst[i];
            int k = d >> 8;
            myk[e] = k;
            mysrc[e] = src[i];
            mypk[e] = ((unsigned)f2bf(val[i]) << 16) | (unsigned)(d & (BK - 1));
            myr[e] = atomicAdd(&cnt[k], 1);
        } else {
            myk[e] = -1;
        }
    }
    __syncthreads();
    // inclusive scan of cnt over K_ (Hillis-Steele, 1024 threads)
    int v = (tid < K_) ? cnt[tid] : 0;
    sh[tid] = v;
    __syncthreads();
    for (int off = 1; off < KMAX; off <<= 1) {
        int t = (tid >= off) ? sh[tid - off] : 0;
        __syncthreads();
        sh[tid] += t;
        __syncthreads();
    }
    // reserve global bucket ranges; gb[k] pre-adjusted by local base
    if (tid < K_ && v) {
        int lbase = sh[tid] - v;
        gb[tid] = (tid * S_ + atomicAdd(&g_pos[tid], v)) - lbase;
    }
    __syncthreads();
    // stage into LDS at block-locally sorted position
#pragma unroll
    for (int e = 0; e < PEPT; ++e) {
        int k = myk[e];
        if (k >= 0) {
            int slot = (sh[k] - cnt[k]) + myr[e];
            stg[slot] = make_int2(mysrc[e] | (k << 20), (int)mypk[e]);
        }
    }
    __syncthreads();
    // coalesced writeout: consecutive slots -> consecutive global positions
    for (int l = tid; l < nc; l += 1024) {
        int2 ev = stg[l];
        int k = (int)((unsigned)ev.x >> 20);
        st[gb[k] + l] = make_int2(ev.x & 0xFFFFF, ev.y);
    }
}

// single block (1024 threads): exclusive scan of K (<=1024) bucket counts.
__global__ void scan_bkt_kernel(const int* __restrict__ cnt,
                                int* __restrict__ base, int K_) {
    __shared__ int sh[KMAX];
    int tid = threadIdx.x;
    int v = (tid < K_) ? cnt[tid] : 0;
    sh[tid] = v;
    __syncthreads();
    for (int off = 1; off < KMAX; off <<= 1) {
        int t = (tid >= off) ? sh[tid - off] : 0;
        __syncthreads();
        sh[tid] += t;
        __syncthreads();
    }
    if (tid < K_) base[tid] = sh[tid] - v;
}

// place: one block per bucket; local degrees + row_span in LDS, then scatter
// from strided st into the compact L2-resident col_val window.
__global__ void place_kernel(const int2* __restrict__ st,
                             const int* __restrict__ g_cnt,
                             const int* __restrict__ bkt_base,
                             int2* __restrict__ row_span,
                             int2* __restrict__ col_val,
                             int S_, int N_) {
    __shared__ int ldeg[BK];
    __shared__ int sh[BK];
    __shared__ int lcur[BK];
    int b = blockIdx.x;
    int tid = threadIdx.x;
    int rbeg = b << 8;
    int sbeg = b * S_;
    int cnt = g_cnt[b];
    int cbeg = bkt_base[b];
    ldeg[tid] = 0;
    __syncthreads();
    for (int i = tid; i < cnt; i += 256)
        atomicAdd(&ldeg[(unsigned)st[sbeg + i].y & (BK - 1u)], 1);
    __syncthreads();
    int v = ldeg[tid];
    sh[tid] = v;
    __syncthreads();
    for (int off = 1; off < BK; off <<= 1) {
        int t = (tid >= off) ? sh[tid - off] : 0;
        __syncthreads();
        sh[tid] += t;
        __syncthreads();
    }
    int excl = sh[tid] - v;
    lcur[tid] = excl;
    int gi = rbeg + tid;
    if (gi < N_) row_span[gi] = make_int2(cbeg + excl, cbeg + excl + v);
    __syncthreads();
    for (int i = tid; i < cnt; i += 256) {
        int2 cv = st[sbeg + i];
        int pcur = cbeg + atomicAdd(&lcur[(unsigned)cv.y & (BK - 1u)], 1);
        col_val[pcur] = cv;
    }
}

// ---------------- shared row-accumulate body ----------------
static __device__ __forceinline__ void spmm_row_body(
        int beg, int end, int lane, int q, int lid,
        const int2* __restrict__ col_val, const uint4* __restrict__ xb,
        float& s0, float& s1, float& s2, float& s3,
        float& s4, float& s5, float& s6, float& s7) {
    for (int base = beg; base < end; base += 64) {
        int e = base + lane;
        int c = 0;
        float v = 0.f;
        if (e < end) {
            int2 cv = col_val[e];
            c = cv.x;
            v = bfhi((unsigned)cv.y);   // val in high 16 bits
        }
        int m8 = (min(64, end - base) + 7) & ~7;
        int j = 0;
        // 2x unroll: two independent gathers in flight per step
        for (; j + 16 <= m8; j += 16) {
            int cj0 = __shfl(c, j + q, 64);
            float vj0 = __shfl(v, j + q, 64);
            int cj1 = __shfl(c, j + 8 + q, 64);
            float vj1 = __shfl(v, j + 8 + q, 64);
            uint4 t0 = xb[cj0 * 8 + lid];
            uint4 t1 = xb[cj1 * 8 + lid];
            s0 += vj0 * bflo(t0.x); s1 += vj0 * bfhi(t0.x);
            s2 += vj0 * bflo(t0.y); s3 += vj0 * bfhi(t0.y);
            s4 += vj0 * bflo(t0.z); s5 += vj0 * bfhi(t0.z);
            s6 += vj0 * bflo(t0.w); s7 += vj0 * bfhi(t0.w);
            s0 += vj1 * bflo(t1.x); s1 += vj1 * bfhi(t1.x);
            s2 += vj1 * bflo(t1.y); s3 += vj1 * bfhi(t1.y);
            s4 += vj1 * bflo(t1.z); s5 += vj1 * bfhi(t1.z);
            s6 += vj1 * bflo(t1.w); s7 += vj1 * bfhi(t1.w);
        }
        if (j < m8) {
            int cj = __shfl(c, j + q, 64);
            float vj = __shfl(v, j + q, 64);
            uint4 t = xb[cj * 8 + lid];
            s0 += vj * bflo(t.x); s1 += vj * bfhi(t.x);
            s2 += vj * bflo(t.y); s3 += vj * bfhi(t.y);
            s4 += vj * bflo(t.z); s5 += vj * bfhi(t.z);
            s6 += vj * bflo(t.w); s7 += vj * bfhi(t.w);
        }
    }
#pragma unroll
    for (int off = 32; off >= 8; off >>= 1) {
        s0 += __shfl_xor(s0, off, 64);
        s1 += __shfl_xor(s1, off, 64);
        s2 += __shfl_xor(s2, off, 64);
        s3 += __shfl_xor(s3, off, 64);
        s4 += __shfl_xor(s4, off, 64);
        s5 += __shfl_xor(s5, off, 64);
        s6 += __shfl_xor(s6, off, 64);
        s7 += __shfl_xor(s7, off, 64);
    }
}

// ---------------- CSR gather SpMM (full layers 1-2) ----------------
__global__ void spmm_csr_kernel(const int2* __restrict__ row_span,
                                const int2* __restrict__ col_val,
                                const uint4* __restrict__ xb,
                                uint4* __restrict__ nxtb,
                                float4* __restrict__ acc,
                                const int* __restrict__ flags,
                                int N_) {
    int row = (int)((blockIdx.x * blockDim.x + threadIdx.x) >> 6);
    int lane = threadIdx.x & 63;
    if (row >= N_) return;
    int q = lane >> 3;
    int lid = lane & 7;
    int2 sp = row_span[row];
    float s0 = 0, s1 = 0, s2 = 0, s3 = 0, s4 = 0, s5 = 0, s6 = 0, s7 = 0;
    spmm_row_body(sp.x, sp.y, lane, q, lid, col_val, xb,
                  s0, s1, s2, s3, s4, s5, s6, s7);
    if (q == 0) {
        uint4 b;
        b.x = (unsigned)f2bf(s0) | ((unsigned)f2bf(s1) << 16);
        b.y = (unsigned)f2bf(s2) | ((unsigned)f2bf(s3) << 16);
        b.z = (unsigned)f2bf(s4) | ((unsigned)f2bf(s5) << 16);
        b.w = (unsigned)f2bf(s6) | ((unsigned)f2bf(s7) << 16);
        nxtb[row * 8 + lid] = b;
        if (flags[row]) {
            float4* ap = acc + row * 16 + lid * 2;
            float4 a0 = ap[0];
            a0.x += s0; a0.y += s1; a0.z += s2; a0.w += s3;
            ap[0] = a0;
            float4 a1 = ap[1];
            a1.x += s4; a1.y += s5; a1.z += s6; a1.w += s7;
            ap[1] = a1;
        }
    }
}

// ---------------- layer-3 SpMM over compacted flagged rows only ----------------
__global__ void spmm_rows_kernel(const int2* __restrict__ row_span,
                                 const int2* __restrict__ col_val,
                                 const uint4* __restrict__ xb,
                                 float4* __restrict__ acc,
                                 const int* __restrict__ list,
                                 const int* __restrict__ n_list) {
    int w = (int)((blockIdx.x * blockDim.x + threadIdx.x) >> 6);
    if (w >= *n_list) return;
    int row = list[w];
    int lane = threadIdx.x & 63;
    int q = lane >> 3;
    int lid = lane & 7;
    int2 sp = row_span[row];
    float s0 = 0, s1 = 0, s2 = 0, s3 = 0, s4 = 0, s5 = 0, s6 = 0, s7 = 0;
    spmm_row_body(sp.x, sp.y, lane, q, lid, col_val, xb,
                  s0, s1, s2, s3, s4, s5, s6, s7);
    if (q == 0) {
        float4* ap = acc + row * 16 + lid * 2;
        float4 a0 = ap[0];
        a0.x += s0; a0.y += s1; a0.z += s2; a0.w += s3;
        ap[0] = a0;
        float4 a1 = ap[1];
        a1.x += s4; a1.y += s5; a1.z += s6; a1.w += s7;
        ap[1] = a1;
    }
}

// ---------------- epilogue ----------------
__global__ void final_kernel(const float* __restrict__ acc,
                             const float* __restrict__ user_w,
                             const float* __restrict__ item_w,
                             const int* __restrict__ bu,
                             const int* __restrict__ bp,
                             const int* __restrict__ bn,
                             float* __restrict__ out,
                             float* __restrict__ red,
                             int U_, int B_) {
    __shared__ float pr[4];
    int w = (int)((blockIdx.x * blockDim.x + threadIdx.x) >> 6);
    int lane = threadIdx.x & 63;
    bool valid = (w < B_);
    float ps = 0.f, ns = 0.f, r = 0.f;
    if (valid) {
        int iu = bu[w], ip = bp[w], in_ = bn[w];
        const float scale = 0.25f;  // 1/(L+1)
        float u = acc[(long)iu * D + lane] * scale;
        float p = acc[(long)(U_ + ip) * D + lane] * scale;
        float g = acc[(long)(U_ + in_) * D + lane] * scale;
        ps = u * p;
        ns = u * g;
        float u0 = user_w[(long)iu * D + lane];
        float p0 = item_w[(long)ip * D + lane];
        float n0 = item_w[(long)in_ * D + lane];
        r = u0 * u0 + p0 * p0 + n0 * n0;
    }
#pragma unroll
    for (int off = 32; off; off >>= 1) {
        ps += __shfl_down(ps, off, 64);
        ns += __shfl_down(ns, off, 64);
        r  += __shfl_down(r, off, 64);
    }
    if (lane == 0) pr[threadIdx.x >> 6] = r;
    __syncthreads();
    if (threadIdx.x == 0)
        red[blockIdx.x] = pr[0] + pr[1] + pr[2] + pr[3];
    if (valid && lane == 0) {
        out[w] = ps;
        out[B_ + w] = ns;
    }
}

// single block: sum nblk partials -> out[2B]
__global__ void reduce_kernel(const float* __restrict__ red,
                              float* __restrict__ out_scalar, int nblk) {
    __shared__ float sh[256];
    float s = 0.f;
    for (int i = threadIdx.x; i < nblk; i += 256) s += red[i];
    sh[threadIdx.x] = s;
    __syncthreads();
    for (int off = 128; off; off >>= 1) {
        if (threadIdx.x < off) sh[threadIdx.x] += sh[threadIdx.x + off];
        __syncthreads();
    }
    if (threadIdx.x == 0) *out_scalar = sh[0];
}

// ---------------- launch ----------------
extern "C" void kernel_launch(void* const* d_in, const int* in_sizes, int n_in,
                              void* d_out, int out_size, void* d_ws, size_t ws_size,
                              hipStream_t stream) {
    const int*   edge_src = (const int*)d_in[0];
    const int*   edge_dst = (const int*)d_in[1];
    const float* edge_val = (const float*)d_in[2];
    const float* user_w   = (const float*)d_in[3];
    const float* item_w   = (const float*)d_in[4];
    const int*   bu       = (const int*)d_in[5];
    const int*   bp       = (const int*)d_in[6];
    const int*   bn       = (const int*)d_in[7];

    int E_ = in_sizes[0];
    int U_ = in_sizes[3] / D;
    int I_ = in_sizes[4] / D;
    int B_ = in_sizes[5];
    int N_ = U_ + I_;
    long ND = (long)N_ * D;
    int K_ = (N_ + BK - 1) >> 8;                       // 256-row dst buckets
    int S_ = ((E_ / K_) * 3 / 2 + 255) & ~255;         // 1.5x mean bucket slack

    // ---- workspace layout ----
    char* p = (char*)d_ws;
    int2* col_val  = (int2*)p;   p += (size_t)E_ * sizeof(int2);
    int2* row_span = (int2*)p;   p += (size_t)N_ * sizeof(int2);
    int*  bkt_base = (int*)p;    p += KMAX * sizeof(int);
    float* red     = (float*)p;  p += 4096 * sizeof(float);
    char* zb = p;                                   // zeroed block start
    int*  g_pos    = (int*)p;    p += KMAX * sizeof(int);
    int*  n_list   = (int*)p;    p += 256;          // padded
    int*  flags    = (int*)p;    p += (size_t)N_ * sizeof(int);
    size_t zbytes  = (size_t)(p - zb);
    int*  list     = (int*)p;    p += (size_t)3 * B_ * sizeof(int);
    p = (char*)(((uintptr_t)p + 255) & ~(uintptr_t)255);
    // overlay: staged edges (build phase) then embeddings (compute phase)
    int2* st = (int2*)p;
    float* acc = (float*)p;
    unsigned short* curb = (unsigned short*)(acc + ND);
    unsigned short* nxtb = curb + ND;
    float* out = (float*)d_out;

    int n4 = (int)(ND / 4);
    int nu4 = U_ * D / 4;

    // ---- CSR build (LDS-staged partition, no count kernel) ----
    hipMemsetAsync(zb, 0, zbytes, stream);
    partition_kernel<<<(E_ + PCH - 1) / PCH, 1024, 0, stream>>>(
        edge_src, edge_dst, edge_val, g_pos, st, S_, K_, E_);
    scan_bkt_kernel<<<1, KMAX, 0, stream>>>(g_pos, bkt_base, K_);
    place_kernel<<<K_, 256, 0, stream>>>(st, g_pos, bkt_base, row_span,
                                         col_val, S_, N_);

    // ---- batch-row flags + compacted list ----
    flag_kernel<<<(3 * B_ + 255) / 256, 256, 0, stream>>>(
        bu, bp, bn, flags, list, n_list, U_, B_);

    // ---- embeddings init (overwrites staged region; stream-ordered) ----
    init_kernel<<<(n4 + 255) / 256, 256, 0, stream>>>(
        (const float4*)user_w, (const float4*)item_w,
        (float4*)acc, (ushort4*)curb, flags, nu4, n4);

    // ---- propagation: layers 1-2 full, layer 3 only batch rows ----
    spmm_csr_kernel<<<(N_ + 3) / 4, 256, 0, stream>>>(
        row_span, col_val, (const uint4*)curb, (uint4*)nxtb, (float4*)acc,
        flags, N_);
    spmm_csr_kernel<<<(N_ + 3) / 4, 256, 0, stream>>>(
        row_span, col_val, (const uint4*)nxtb, (uint4*)curb, (float4*)acc,
        flags, N_);
    spmm_rows_kernel<<<(3 * B_ + 3) / 4, 256, 0, stream>>>(
        row_span, col_val, (const uint4*)curb, (float4*)acc, list, n_list);

    // ---- epilogue ----
    int nblk = (B_ * 64 + 255) / 256;
    final_kernel<<<nblk, 256, 0, stream>>>(
        acc, user_w, item_w, bu, bp, bn, out, red, U_, B_);
    reduce_kernel<<<1, 256, 0, stream>>>(red, out + 2 * B_, nblk);
}

// Round 4
// 402.447 us; speedup vs baseline: 1.4617x; 1.0159x over previous
//
#include <hip/hip_runtime.h>

#define D 64
#define BK 256     // rows per dst bucket
#define KMAX 1024  // max bucket count supported
#define PCH 6144   // edges per partition block (LDS staging = 48 KB)
#define PEPT 6     // edges per thread (1024 threads)

// ---- bf16 helpers ----
static __device__ __forceinline__ unsigned short f2bf(float f) {
    unsigned int u = __float_as_uint(f);
    unsigned int r = (u + 0x7FFFu + ((u >> 16) & 1u)) >> 16;
    return (unsigned short)r;
}
static __device__ __forceinline__ float bflo(unsigned int u) {
    return __uint_as_float(u << 16);
}
static __device__ __forceinline__ float bfhi(unsigned int u) {
    return __uint_as_float(u & 0xFFFF0000u);
}

// ---------------- init: fp32 acc (flagged rows only) + bf16 cur ----------------
__global__ void init_kernel(const float4* __restrict__ user_w,
                            const float4* __restrict__ item_w,
                            float4* __restrict__ acc,
                            ushort4* __restrict__ curb,
                            const int* __restrict__ flags,
                            int n_user4, int n_tot4) {
    int i = blockIdx.x * blockDim.x + threadIdx.x;
    if (i >= n_tot4) return;
    float4 v = (i < n_user4) ? user_w[i] : item_w[i - n_user4];
    ushort4 b;
    b.x = f2bf(v.x); b.y = f2bf(v.y); b.z = f2bf(v.z); b.w = f2bf(v.w);
    curb[i] = b;
    if (flags[i >> 4]) acc[i] = v;   // acc only read at flagged rows
}

// ---------------- flag + compact list of batch-needed rows ----------------
__global__ void flag_kernel(const int* __restrict__ bu,
                            const int* __restrict__ bp,
                            const int* __restrict__ bn,
                            int* __restrict__ flags,
                            int* __restrict__ list,
                            int* __restrict__ n_list,
                            int U_, int B_) {
    int t = blockIdx.x * blockDim.x + threadIdx.x;
    int node = -1;
    if (t < 3 * B_) {
        if (t < B_)            node = bu[t];
        else if (t < 2 * B_)   node = U_ + bp[t - B_];
        else                   node = U_ + bn[t - 2 * B_];
    }
    int old = 1;
    if (node >= 0) old = atomicExch(&flags[node], 1);
    unsigned long long m = __ballot(old == 0);
    int lane = threadIdx.x & 63;
    int myoff = __popcll(m & ((1ull << lane) - 1ull));
    int total = __popcll(m);
    int bse = 0;
    if (lane == 0 && total) bse = atomicAdd(n_list, total);
    bse = __shfl(bse, 0, 64);
    if (old == 0) list[bse + myoff] = node;
}

// ---------------- partition: LDS-staged bucket sort, coalesced writeout ----
// st entry: {src, (val_bf16<<16) | dst_off8}. Bucket k occupies st[k*S .. ).
// Staged entry packs bucket id into src high bits (needs N < 2^20, K <= 1024).
// LDS: 48 KB staging + 12 KB aux = 60 KB -> 2 blocks/CU (120/160 KB).
__global__ void __launch_bounds__(1024)
partition_kernel(const int* __restrict__ src,
                 const int* __restrict__ dst,
                 const float* __restrict__ val,
                 int* __restrict__ g_pos,
                 int2* __restrict__ st,
                 int S_, int K_, int E_) {
    __shared__ int2 stg[PCH];     // block-local bucket-sorted staging
    __shared__ int cnt[KMAX];
    __shared__ int sh[KMAX];      // inclusive scan of cnt
    __shared__ int gb[KMAX];      // global base minus local base
    int tid = threadIdx.x;
    for (int k = tid; k < K_; k += 1024) cnt[k] = 0;
    __syncthreads();
    int b0 = blockIdx.x * PCH;
    int nc = min(PCH, E_ - b0);
    int myk[PEPT], myr[PEPT], mysrc[PEPT];
    unsigned mypk[PEPT];
#pragma unroll
    for (int e = 0; e < PEPT; ++e) {
        int i = b0 + e * 1024 + tid;
        if (i < E_) {
            int d = dst[i];
            int k = d >> 8;
            myk[e] = k;
            mysrc[e] = src[i];
            mypk[e] = ((unsigned)f2bf(val[i]) << 16) | (unsigned)(d & (BK - 1));
            myr[e] = atomicAdd(&cnt[k], 1);
        } else {
            myk[e] = -1;
        }
    }
    __syncthreads();
    // inclusive scan of cnt over K_ (Hillis-Steele, 1024 threads)
    int v = (tid < K_) ? cnt[tid] : 0;
    sh[tid] = v;
    __syncthreads();
    for (int off = 1; off < KMAX; off <<= 1) {
        int t = (tid >= off) ? sh[tid - off] : 0;
        __syncthreads();
        sh[tid] += t;
        __syncthreads();
    }
    // reserve global bucket ranges; gb[k] pre-adjusted by local base
    if (tid < K_ && v) {
        int lbase = sh[tid] - v;
        gb[tid] = (tid * S_ + atomicAdd(&g_pos[tid], v)) - lbase;
    }
    __syncthreads();
    // stage into LDS at block-locally sorted position
#pragma unroll
    for (int e = 0; e < PEPT; ++e) {
        int k = myk[e];
        if (k >= 0) {
            int slot = (sh[k] - cnt[k]) + myr[e];
            stg[slot] = make_int2(mysrc[e] | (k << 20), (int)mypk[e]);
        }
    }
    __syncthreads();
    // coalesced writeout: consecutive slots -> consecutive global positions
    for (int l = tid; l < nc; l += 1024) {
        int2 ev = stg[l];
        int k = (int)((unsigned)ev.x >> 20);
        st[gb[k] + l] = make_int2(ev.x & 0xFFFFF, ev.y);
    }
}

// single block (1024 threads): exclusive scan of K (<=1024) bucket counts.
__global__ void scan_bkt_kernel(const int* __restrict__ cnt,
                                int* __restrict__ base, int K_) {
    __shared__ int sh[KMAX];
    int tid = threadIdx.x;
    int v = (tid < K_) ? cnt[tid] : 0;
    sh[tid] = v;
    __syncthreads();
    for (int off = 1; off < KMAX; off <<= 1) {
        int t = (tid >= off) ? sh[tid - off] : 0;
        __syncthreads();
        sh[tid] += t;
        __syncthreads();
    }
    if (tid < K_) base[tid] = sh[tid] - v;
}

// place: one block per bucket (1024 threads for latency hiding); local degrees
// + row_span in LDS, then scatter from strided st into the compact col_val
// window (L2-resident; second st read also L2-hits).
__global__ void __launch_bounds__(1024)
place_kernel(const int2* __restrict__ st,
             const int* __restrict__ g_cnt,
             const int* __restrict__ bkt_base,
             int2* __restrict__ row_span,
             int2* __restrict__ col_val,
             int S_, int N_) {
    __shared__ int ldeg[BK];
    __shared__ int sh[BK];
    __shared__ int lcur[BK];
    int b = blockIdx.x;
    int tid = threadIdx.x;
    int rbeg = b << 8;
    int sbeg = b * S_;
    int cnt = g_cnt[b];
    int cbeg = bkt_base[b];
    if (tid < BK) ldeg[tid] = 0;
    __syncthreads();
    for (int i = tid; i < cnt; i += 1024)
        atomicAdd(&ldeg[(unsigned)st[sbeg + i].y & (BK - 1u)], 1);
    __syncthreads();
    int v = 0;
    if (tid < BK) {
        v = ldeg[tid];
        sh[tid] = v;
    }
    __syncthreads();
    for (int off = 1; off < BK; off <<= 1) {
        int t = (tid < BK && tid >= off) ? sh[tid - off] : 0;
        __syncthreads();
        if (tid < BK) sh[tid] += t;
        __syncthreads();
    }
    if (tid < BK) {
        int excl = sh[tid] - v;
        lcur[tid] = excl;
        int gi = rbeg + tid;
        if (gi < N_) row_span[gi] = make_int2(cbeg + excl, cbeg + excl + v);
    }
    __syncthreads();
    for (int i = tid; i < cnt; i += 1024) {
        int2 cv = st[sbeg + i];
        int pcur = cbeg + atomicAdd(&lcur[(unsigned)cv.y & (BK - 1u)], 1);
        col_val[pcur] = cv;
    }
}

// ---------------- shared row-accumulate body ----------------
// Issues ALL (up to 8) 8-edge-group gathers of a 64-edge chunk back-to-back,
// then consumes: 4-8 gathers in flight per wave (vs 2 before) -> latency hiding.
// nq guards are wave-uniform; t0..t7 are named regs (no scratch).
static __device__ __forceinline__ void spmm_row_body(
        int beg, int end, int lane, int q, int lid,
        const int2* __restrict__ col_val, const uint4* __restrict__ xb,
        float& s0, float& s1, float& s2, float& s3,
        float& s4, float& s5, float& s6, float& s7) {
    for (int base = beg; base < end; base += 64) {
        int e = base + lane;
        int c = 0;
        float v = 0.f;
        if (e < end) {
            int2 cv = col_val[e];
            c = cv.x;
            v = bfhi((unsigned)cv.y);   // val in high 16 bits
        }
        int nq = (min(64, end - base) + 7) >> 3;   // 1..8 groups of 8 edges
        uint4 t0, t1, t2, t3, t4, t5, t6, t7;
        float w0, w1, w2, w3, w4, w5, w6, w7;
        // ---- issue phase ----
        { int cj = __shfl(c, q, 64);      w0 = __shfl(v, q, 64);      t0 = xb[cj * 8 + lid]; }
        if (nq > 1) { int cj = __shfl(c, 8 + q, 64);  w1 = __shfl(v, 8 + q, 64);  t1 = xb[cj * 8 + lid]; }
        if (nq > 2) { int cj = __shfl(c, 16 + q, 64); w2 = __shfl(v, 16 + q, 64); t2 = xb[cj * 8 + lid]; }
        if (nq > 3) { int cj = __shfl(c, 24 + q, 64); w3 = __shfl(v, 24 + q, 64); t3 = xb[cj * 8 + lid]; }
        if (nq > 4) { int cj = __shfl(c, 32 + q, 64); w4 = __shfl(v, 32 + q, 64); t4 = xb[cj * 8 + lid]; }
        if (nq > 5) { int cj = __shfl(c, 40 + q, 64); w5 = __shfl(v, 40 + q, 64); t5 = xb[cj * 8 + lid]; }
        if (nq > 6) { int cj = __shfl(c, 48 + q, 64); w6 = __shfl(v, 48 + q, 64); t6 = xb[cj * 8 + lid]; }
        if (nq > 7) { int cj = __shfl(c, 56 + q, 64); w7 = __shfl(v, 56 + q, 64); t7 = xb[cj * 8 + lid]; }
        // ---- consume phase ----
#define ACC8(W, T) \
        s0 += (W) * bflo((T).x); s1 += (W) * bfhi((T).x); \
        s2 += (W) * bflo((T).y); s3 += (W) * bfhi((T).y); \
        s4 += (W) * bflo((T).z); s5 += (W) * bfhi((T).z); \
        s6 += (W) * bflo((T).w); s7 += (W) * bfhi((T).w);
        { ACC8(w0, t0) }
        if (nq > 1) { ACC8(w1, t1) }
        if (nq > 2) { ACC8(w2, t2) }
        if (nq > 3) { ACC8(w3, t3) }
        if (nq > 4) { ACC8(w4, t4) }
        if (nq > 5) { ACC8(w5, t5) }
        if (nq > 6) { ACC8(w6, t6) }
        if (nq > 7) { ACC8(w7, t7) }
#undef ACC8
    }
#pragma unroll
    for (int off = 32; off >= 8; off >>= 1) {
        s0 += __shfl_xor(s0, off, 64);
        s1 += __shfl_xor(s1, off, 64);
        s2 += __shfl_xor(s2, off, 64);
        s3 += __shfl_xor(s3, off, 64);
        s4 += __shfl_xor(s4, off, 64);
        s5 += __shfl_xor(s5, off, 64);
        s6 += __shfl_xor(s6, off, 64);
        s7 += __shfl_xor(s7, off, 64);
    }
}

// ---------------- CSR gather SpMM (full layers 1-2) ----------------
__global__ void spmm_csr_kernel(const int2* __restrict__ row_span,
                                const int2* __restrict__ col_val,
                                const uint4* __restrict__ xb,
                                uint4* __restrict__ nxtb,
                                float4* __restrict__ acc,
                                const int* __restrict__ flags,
                                int N_) {
    int row = (int)((blockIdx.x * blockDim.x + threadIdx.x) >> 6);
    int lane = threadIdx.x & 63;
    if (row >= N_) return;
    int q = lane >> 3;
    int lid = lane & 7;
    int2 sp = row_span[row];
    float s0 = 0, s1 = 0, s2 = 0, s3 = 0, s4 = 0, s5 = 0, s6 = 0, s7 = 0;
    spmm_row_body(sp.x, sp.y, lane, q, lid, col_val, xb,
                  s0, s1, s2, s3, s4, s5, s6, s7);
    if (q == 0) {
        uint4 b;
        b.x = (unsigned)f2bf(s0) | ((unsigned)f2bf(s1) << 16);
        b.y = (unsigned)f2bf(s2) | ((unsigned)f2bf(s3) << 16);
        b.z = (unsigned)f2bf(s4) | ((unsigned)f2bf(s5) << 16);
        b.w = (unsigned)f2bf(s6) | ((unsigned)f2bf(s7) << 16);
        nxtb[row * 8 + lid] = b;
        if (flags[row]) {
            float4* ap = acc + row * 16 + lid * 2;
            float4 a0 = ap[0];
            a0.x += s0; a0.y += s1; a0.z += s2; a0.w += s3;
            ap[0] = a0;
            float4 a1 = ap[1];
            a1.x += s4; a1.y += s5; a1.z += s6; a1.w += s7;
            ap[1] = a1;
        }
    }
}

// ---------------- layer-3 SpMM over compacted flagged rows only ----------------
__global__ void spmm_rows_kernel(const int2* __restrict__ row_span,
                                 const int2* __restrict__ col_val,
                                 const uint4* __restrict__ xb,
                                 float4* __restrict__ acc,
                                 const int* __restrict__ list,
                                 const int* __restrict__ n_list) {
    int w = (int)((blockIdx.x * blockDim.x + threadIdx.x) >> 6);
    if (w >= *n_list) return;
    int row = list[w];
    int lane = threadIdx.x & 63;
    int q = lane >> 3;
    int lid = lane & 7;
    int2 sp = row_span[row];
    float s0 = 0, s1 = 0, s2 = 0, s3 = 0, s4 = 0, s5 = 0, s6 = 0, s7 = 0;
    spmm_row_body(sp.x, sp.y, lane, q, lid, col_val, xb,
                  s0, s1, s2, s3, s4, s5, s6, s7);
    if (q == 0) {
        float4* ap = acc + row * 16 + lid * 2;
        float4 a0 = ap[0];
        a0.x += s0; a0.y += s1; a0.z += s2; a0.w += s3;
        ap[0] = a0;
        float4 a1 = ap[1];
        a1.x += s4; a1.y += s5; a1.z += s6; a1.w += s7;
        ap[1] = a1;
    }
}

// ---------------- epilogue ----------------
__global__ void final_kernel(const float* __restrict__ acc,
                             const float* __restrict__ user_w,
                             const float* __restrict__ item_w,
                             const int* __restrict__ bu,
                             const int* __restrict__ bp,
                             const int* __restrict__ bn,
                             float* __restrict__ out,
                             float* __restrict__ red,
                             int U_, int B_) {
    __shared__ float pr[4];
    int w = (int)((blockIdx.x * blockDim.x + threadIdx.x) >> 6);
    int lane = threadIdx.x & 63;
    bool valid = (w < B_);
    float ps = 0.f, ns = 0.f, r = 0.f;
    if (valid) {
        int iu = bu[w], ip = bp[w], in_ = bn[w];
        const float scale = 0.25f;  // 1/(L+1)
        float u = acc[(long)iu * D + lane] * scale;
        float p = acc[(long)(U_ + ip) * D + lane] * scale;
        float g = acc[(long)(U_ + in_) * D + lane] * scale;
        ps = u * p;
        ns = u * g;
        float u0 = user_w[(long)iu * D + lane];
        float p0 = item_w[(long)ip * D + lane];
        float n0 = item_w[(long)in_ * D + lane];
        r = u0 * u0 + p0 * p0 + n0 * n0;
    }
#pragma unroll
    for (int off = 32; off; off >>= 1) {
        ps += __shfl_down(ps, off, 64);
        ns += __shfl_down(ns, off, 64);
        r  += __shfl_down(r, off, 64);
    }
    if (lane == 0) pr[threadIdx.x >> 6] = r;
    __syncthreads();
    if (threadIdx.x == 0)
        red[blockIdx.x] = pr[0] + pr[1] + pr[2] + pr[3];
    if (valid && lane == 0) {
        out[w] = ps;
        out[B_ + w] = ns;
    }
}

// single block: sum nblk partials -> out[2B]
__global__ void reduce_kernel(const float* __restrict__ red,
                              float* __restrict__ out_scalar, int nblk) {
    __shared__ float sh[256];
    float s = 0.f;
    for (int i = threadIdx.x; i < nblk; i += 256) s += red[i];
    sh[threadIdx.x] = s;
    __syncthreads();
    for (int off = 128; off; off >>= 1) {
        if (threadIdx.x < off) sh[threadIdx.x] += sh[threadIdx.x + off];
        __syncthreads();
    }
    if (threadIdx.x == 0) *out_scalar = sh[0];
}

// ---------------- launch ----------------
extern "C" void kernel_launch(void* const* d_in, const int* in_sizes, int n_in,
                              void* d_out, int out_size, void* d_ws, size_t ws_size,
                              hipStream_t stream) {
    const int*   edge_src = (const int*)d_in[0];
    const int*   edge_dst = (const int*)d_in[1];
    const float* edge_val = (const float*)d_in[2];
    const float* user_w   = (const float*)d_in[3];
    const float* item_w   = (const float*)d_in[4];
    const int*   bu       = (const int*)d_in[5];
    const int*   bp       = (const int*)d_in[6];
    const int*   bn       = (const int*)d_in[7];

    int E_ = in_sizes[0];
    int U_ = in_sizes[3] / D;
    int I_ = in_sizes[4] / D;
    int B_ = in_sizes[5];
    int N_ = U_ + I_;
    long ND = (long)N_ * D;
    int K_ = (N_ + BK - 1) >> 8;                       // 256-row dst buckets
    int S_ = ((E_ / K_) * 3 / 2 + 255) & ~255;         // 1.5x mean bucket slack

    // ---- workspace layout ----
    char* p = (char*)d_ws;
    int2* col_val  = (int2*)p;   p += (size_t)E_ * sizeof(int2);
    int2* row_span = (int2*)p;   p += (size_t)N_ * sizeof(int2);
    int*  bkt_base = (int*)p;    p += KMAX * sizeof(int);
    float* red     = (float*)p;  p += 4096 * sizeof(float);
    char* zb = p;                                   // zeroed block start
    int*  g_pos    = (int*)p;    p += KMAX * sizeof(int);
    int*  n_list   = (int*)p;    p += 256;          // padded
    int*  flags    = (int*)p;    p += (size_t)N_ * sizeof(int);
    size_t zbytes  = (size_t)(p - zb);
    int*  list     = (int*)p;    p += (size_t)3 * B_ * sizeof(int);
    p = (char*)(((uintptr_t)p + 255) & ~(uintptr_t)255);
    // overlay: staged edges (build phase) then embeddings (compute phase)
    int2* st = (int2*)p;
    float* acc = (float*)p;
    unsigned short* curb = (unsigned short*)(acc + ND);
    unsigned short* nxtb = curb + ND;
    float* out = (float*)d_out;

    int n4 = (int)(ND / 4);
    int nu4 = U_ * D / 4;

    // ---- CSR build (LDS-staged partition, no count kernel) ----
    hipMemsetAsync(zb, 0, zbytes, stream);
    partition_kernel<<<(E_ + PCH - 1) / PCH, 1024, 0, stream>>>(
        edge_src, edge_dst, edge_val, g_pos, st, S_, K_, E_);
    scan_bkt_kernel<<<1, KMAX, 0, stream>>>(g_pos, bkt_base, K_);
    place_kernel<<<K_, 1024, 0, stream>>>(st, g_pos, bkt_base, row_span,
                                          col_val, S_, N_);

    // ---- batch-row flags + compacted list ----
    flag_kernel<<<(3 * B_ + 255) / 256, 256, 0, stream>>>(
        bu, bp, bn, flags, list, n_list, U_, B_);

    // ---- embeddings init (overwrites staged region; stream-ordered) ----
    init_kernel<<<(n4 + 255) / 256, 256, 0, stream>>>(
        (const float4*)user_w, (const float4*)item_w,
        (float4*)acc, (ushort4*)curb, flags, nu4, n4);

    // ---- propagation: layers 1-2 full, layer 3 only batch rows ----
    spmm_csr_kernel<<<(N_ + 3) / 4, 256, 0, stream>>>(
        row_span, col_val, (const uint4*)curb, (uint4*)nxtb, (float4*)acc,
        flags, N_);
    spmm_csr_kernel<<<(N_ + 3) / 4, 256, 0, stream>>>(
        row_span, col_val, (const uint4*)nxtb, (uint4*)curb, (float4*)acc,
        flags, N_);
    spmm_rows_kernel<<<(3 * B_ + 3) / 4, 256, 0, stream>>>(
        row_span, col_val, (const uint4*)curb, (float4*)acc, list, n_list);

    // ---- epilogue ----
    int nblk = (B_ * 64 + 255) / 256;
    final_kernel<<<nblk, 256, 0, stream>>>(
        acc, user_w, item_w, bu, bp, bn, out, red, U_, B_);
    reduce_kernel<<<1, 256, 0, stream>>>(red, out + 2 * B_, nblk);
}